// Round 5
// baseline (373.124 us; speedup 1.0000x reference)
//
#include <hip/hip_runtime.h>
#include <math.h>

typedef unsigned int u32;

#define NN   40000
#define EE   640000
#define FD   128
#define HD   128
#define SUBG 400
#define CELLS 100
#define BNEPS 1e-5f
#define NPB  157   // ceil(NN/256)
#define STATB 160  // bnstats blocks

// ---- bf16 helpers (pack with RNE, unpack via bit-shift) ----
__device__ __forceinline__ u32 bf16pair(float a, float b) {
    u32 ua = __float_as_uint(a), ub = __float_as_uint(b);
    ua += 0x7fffu + ((ua >> 16) & 1u);
    ub += 0x7fffu + ((ub >> 16) & 1u);
    return (ua >> 16) | (ub & 0xffff0000u);
}
__device__ __forceinline__ float bflo(u32 u) { return __uint_as_float(u << 16); }
__device__ __forceinline__ float bfhi(u32 u) { return __uint_as_float(u & 0xffff0000u); }

// ---------------- CSR build ----------------
__global__ void k_zeroi(int* p, int n) {
    int i = blockIdx.x * blockDim.x + threadIdx.x;
    if (i < n) p[i] = 0;
}

__global__ void k_degcount(const int* __restrict__ dst, int* __restrict__ deg) {
    int i = blockIdx.x * blockDim.x + threadIdx.x;
    int stride = gridDim.x * blockDim.x;
    for (; i < EE; i += stride) atomicAdd(&deg[dst[i]], 1);
}

__global__ void k_scan1(const int* __restrict__ deg, int* __restrict__ excl,
                        int* __restrict__ part) {
    __shared__ int s[256];
    int t = threadIdx.x;
    int i = blockIdx.x * 256 + t;
    int v = (i < NN) ? deg[i] : 0;
    s[t] = v;
    __syncthreads();
    for (int off = 1; off < 256; off <<= 1) {
        int add = (t >= off) ? s[t - off] : 0;
        __syncthreads();
        s[t] += add;
        __syncthreads();
    }
    if (i < NN) excl[i] = s[t] - v;
    if (t == 255) part[blockIdx.x] = s[255];
}

__global__ void k_scan2(int* __restrict__ part, int* __restrict__ partx) {
    __shared__ int s[256];
    int t = threadIdx.x;
    int v = (t < NPB) ? part[t] : 0;
    s[t] = v;
    __syncthreads();
    for (int off = 1; off < 256; off <<= 1) {
        int add = (t >= off) ? s[t - off] : 0;
        __syncthreads();
        s[t] += add;
        __syncthreads();
    }
    if (t < NPB) partx[t] = s[t] - v;
}

__global__ void k_scan3(const int* __restrict__ excl, const int* __restrict__ partx,
                        const int* __restrict__ deg, int* __restrict__ rowstart,
                        float* __restrict__ dis) {
    int i = blockIdx.x * 256 + threadIdx.x;
    if (i < NN) {
        rowstart[i] = excl[i] + partx[blockIdx.x];
        dis[i] = rsqrtf((float)(deg[i] + 1));   // +1 self-loop
    }
    if (i == 0) rowstart[NN] = EE;
}

__global__ void k_fill(const int* __restrict__ src, const int* __restrict__ dst,
                       const int* __restrict__ rowstart, int* __restrict__ cursor,
                       int* __restrict__ csr_src) {
    int i = blockIdx.x * blockDim.x + threadIdx.x;
    int stride = gridDim.x * blockDim.x;
    for (; i < EE; i += stride) {
        int d = dst[i];
        int slot = rowstart[d] + atomicAdd(&cursor[d], 1);
        csr_src[slot] = src[i];
    }
}

// ---------------- tiled GEMM  Yb[M,128](bf16) = X[M,128] @ W[128,128] ----------------
// 64-row LDS tile float4[64][32] linear; thread = 8 rows x 4 cols, float4 acc[8].
// Optional fused input BN+ReLU during staging (ss != nullptr). Output packed bf16.
__global__ __launch_bounds__(256, 2)
void k_gemm128(const float* __restrict__ X, const float* __restrict__ W,
               u32* __restrict__ Yb, const float* __restrict__ ss) {
    __shared__ float4 xs[64 * 32];   // 32 KB
    int t = threadIdx.x;
    long rowbase = (long)blockIdx.x * 64;
    const float4* Xv = (const float4*)(X + rowbase * 128);
    if (ss) {
#pragma unroll
        for (int i = 0; i < 8; ++i) {
            int f = t + 256 * i;
            int c4 = (f & 31) * 4;
            float4 v = Xv[f];
            float4 sc = *(const float4*)&ss[c4];
            float4 sh = *(const float4*)&ss[128 + c4];
            v.x = fmaxf(fmaf(v.x, sc.x, sh.x), 0.f);
            v.y = fmaxf(fmaf(v.y, sc.y, sh.y), 0.f);
            v.z = fmaxf(fmaf(v.z, sc.z, sh.z), 0.f);
            v.w = fmaxf(fmaf(v.w, sc.w, sh.w), 0.f);
            xs[f] = v;
        }
    } else {
#pragma unroll
        for (int i = 0; i < 8; ++i)
            xs[t + 256 * i] = Xv[t + 256 * i];
    }
    __syncthreads();

    int cg = t & 31;            // col group: cols cg*4 .. cg*4+3
    int r0 = (t >> 5) * 8;      // 8 rows
    const float4* Wv = (const float4*)W;

    float4 acc[8];
#pragma unroll
    for (int i = 0; i < 8; ++i) acc[i] = make_float4(0.f, 0.f, 0.f, 0.f);

    for (int k4 = 0; k4 < 32; ++k4) {
        float4 w0 = Wv[(4 * k4 + 0) * 32 + cg];
        float4 w1 = Wv[(4 * k4 + 1) * 32 + cg];
        float4 w2 = Wv[(4 * k4 + 2) * 32 + cg];
        float4 w3 = Wv[(4 * k4 + 3) * 32 + cg];
#pragma unroll
        for (int i = 0; i < 8; ++i) {
            float4 xv = xs[(r0 + i) * 32 + k4];
            acc[i].x = fmaf(xv.x, w0.x, acc[i].x);
            acc[i].x = fmaf(xv.y, w1.x, acc[i].x);
            acc[i].x = fmaf(xv.z, w2.x, acc[i].x);
            acc[i].x = fmaf(xv.w, w3.x, acc[i].x);
            acc[i].y = fmaf(xv.x, w0.y, acc[i].y);
            acc[i].y = fmaf(xv.y, w1.y, acc[i].y);
            acc[i].y = fmaf(xv.z, w2.y, acc[i].y);
            acc[i].y = fmaf(xv.w, w3.y, acc[i].y);
            acc[i].z = fmaf(xv.x, w0.z, acc[i].z);
            acc[i].z = fmaf(xv.y, w1.z, acc[i].z);
            acc[i].z = fmaf(xv.z, w2.z, acc[i].z);
            acc[i].z = fmaf(xv.w, w3.z, acc[i].z);
            acc[i].w = fmaf(xv.x, w0.w, acc[i].w);
            acc[i].w = fmaf(xv.y, w1.w, acc[i].w);
            acc[i].w = fmaf(xv.z, w2.w, acc[i].w);
            acc[i].w = fmaf(xv.w, w3.w, acc[i].w);
        }
    }
    u32* yout = Yb + (rowbase + r0) * 64 + cg * 2;
#pragma unroll
    for (int i = 0; i < 8; ++i) {
        uint2 p;
        p.x = bf16pair(acc[i].x, acc[i].y);
        p.y = bf16pair(acc[i].z, acc[i].w);
        *(uint2*)&yout[i * 64] = p;
    }
}

// ---------------- GCN aggregation: bf16 CSR gather, fused self-loop + bias ----------------
// out[d,:] = dis[d] * ( sum_s dis[s]*h[s,:] + dis[d]*h[d,:] ) + bias ; h in bf16
__global__ void k_gather(const u32* __restrict__ Hb, const int* __restrict__ rowstart,
                         const int* __restrict__ csr_src, const float* __restrict__ dis,
                         const float* __restrict__ bias, float* __restrict__ out) {
    int lane = threadIdx.x & 63;
    int node = (blockIdx.x * blockDim.x + threadIdx.x) >> 6;
    if (node >= NN) return;
    float dd = dis[node];
    u32 u0 = Hb[node * 64 + lane];
    float ax = bflo(u0) * dd, ay = bfhi(u0) * dd;
    int e  = rowstart[node];
    int e1 = rowstart[node + 1];
    for (; e + 3 < e1; e += 4) {
        int s0 = csr_src[e], s1 = csr_src[e + 1], s2 = csr_src[e + 2], s3 = csr_src[e + 3];
        float d0 = dis[s0], d1 = dis[s1], d2 = dis[s2], d3 = dis[s3];
        u32 a = Hb[s0 * 64 + lane];
        u32 b = Hb[s1 * 64 + lane];
        u32 c = Hb[s2 * 64 + lane];
        u32 d = Hb[s3 * 64 + lane];
        ax = fmaf(bflo(a), d0, ax); ay = fmaf(bfhi(a), d0, ay);
        ax = fmaf(bflo(b), d1, ax); ay = fmaf(bfhi(b), d1, ay);
        ax = fmaf(bflo(c), d2, ax); ay = fmaf(bfhi(c), d2, ay);
        ax = fmaf(bflo(d), d3, ax); ay = fmaf(bfhi(d), d3, ay);
    }
    for (; e < e1; ++e) {
        int s0 = csr_src[e];
        float d0 = dis[s0];
        u32 a = Hb[s0 * 64 + lane];
        ax = fmaf(bflo(a), d0, ax); ay = fmaf(bfhi(a), d0, ay);
    }
    float2 b2 = *(const float2*)&bias[2 * lane];
    float2 o = { fmaf(ax, dd, b2.x), fmaf(ay, dd, b2.y) };
    *(float2*)&out[(long)node * 128 + 2 * lane] = o;
}

// ---------------- BatchNorm stats: per-block partials (no atomics) ----------------
__global__ void k_bnstats(const float* __restrict__ X, float* __restrict__ part,
                          int rowsPerBlock) {
    __shared__ float ls[256], ls2[256];
    int t = threadIdx.x;
    int col = t & 127, half = t >> 7;
    int r0 = blockIdx.x * rowsPerBlock;
    int r1 = r0 + rowsPerBlock; if (r1 > NN) r1 = NN;
    float s = 0.f, s2 = 0.f;
    for (int r = r0 + half; r < r1; r += 2) {
        float v = X[(long)r * 128 + col];
        s += v; s2 += v * v;
    }
    ls[t] = s; ls2[t] = s2;
    __syncthreads();
    if (t < 128) {
        part[blockIdx.x * 256 + t]       = ls[t]  + ls[t + 128];
        part[blockIdx.x * 256 + 128 + t] = ls2[t] + ls2[t + 128];
    }
}

__global__ void k_bnfinal(const float* __restrict__ part, const float* __restrict__ g,
                          const float* __restrict__ b, float* __restrict__ ss) {
    __shared__ float acc[512];
    int t = threadIdx.x;           // 256
    int c = t & 127, half = t >> 7;
    float s = 0.f, s2 = 0.f;
    for (int bb = half; bb < STATB; bb += 2) {
        s  += part[bb * 256 + c];
        s2 += part[bb * 256 + 128 + c];
    }
    acc[t] = s; acc[256 + t] = s2;
    __syncthreads();
    if (t < 128) {
        float S  = acc[t] + acc[t + 128];
        float S2 = acc[256 + t] + acc[256 + t + 128];
        float mean = S * (1.0f / NN);
        float var  = S2 * (1.0f / NN) - mean * mean;
        float scale = g[t] * rsqrtf(var + BNEPS);
        ss[t] = scale;
        ss[128 + t] = b[t] - mean * scale;
    }
}

// ---------------- fused BN2+ReLU + emb write + attention scores ----------------
__global__ __launch_bounds__(256, 2)
void k_scores(const float* __restrict__ X, const float* __restrict__ ss,
              float* __restrict__ emb,
              const float* __restrict__ w1, const float* __restrict__ b1,
              const float* __restrict__ w2, const float* __restrict__ b2,
              float* __restrict__ scores) {
    __shared__ float4 xs[64 * 32];  // 32 KB
    int t = threadIdx.x;
    long rowbase = (long)blockIdx.x * 64;
    const float4* Xv = (const float4*)(X + rowbase * 128);
    float4* Ev = (float4*)(emb + rowbase * 128);
#pragma unroll
    for (int i = 0; i < 8; ++i) {
        int f = t + 256 * i;
        int c4 = (f & 31) * 4;
        float4 v = Xv[f];
        float4 sc = *(const float4*)&ss[c4];
        float4 sh = *(const float4*)&ss[128 + c4];
        v.x = fmaxf(fmaf(v.x, sc.x, sh.x), 0.f);
        v.y = fmaxf(fmaf(v.y, sc.y, sh.y), 0.f);
        v.z = fmaxf(fmaf(v.z, sc.z, sh.z), 0.f);
        v.w = fmaxf(fmaf(v.w, sc.w, sh.w), 0.f);
        Ev[f] = v;
        xs[f] = v;
    }
    __syncthreads();

    int cg = t & 15;            // col group: cols cg*4 .. +3 (of 64)
    int r0 = (t >> 4) * 4;      // 4 rows
    const float4* Wv = (const float4*)w1;
    float4 bb = ((const float4*)b1)[cg];

    float4 acc[4];
#pragma unroll
    for (int i = 0; i < 4; ++i) acc[i] = bb;

    for (int k4 = 0; k4 < 32; ++k4) {
        float4 w0 = Wv[(4 * k4 + 0) * 16 + cg];
        float4 w1v = Wv[(4 * k4 + 1) * 16 + cg];
        float4 w2v = Wv[(4 * k4 + 2) * 16 + cg];
        float4 w3 = Wv[(4 * k4 + 3) * 16 + cg];
#pragma unroll
        for (int i = 0; i < 4; ++i) {
            float4 xv = xs[(r0 + i) * 32 + k4];
            acc[i].x = fmaf(xv.x, w0.x, acc[i].x);
            acc[i].x = fmaf(xv.y, w1v.x, acc[i].x);
            acc[i].x = fmaf(xv.z, w2v.x, acc[i].x);
            acc[i].x = fmaf(xv.w, w3.x, acc[i].x);
            acc[i].y = fmaf(xv.x, w0.y, acc[i].y);
            acc[i].y = fmaf(xv.y, w1v.y, acc[i].y);
            acc[i].y = fmaf(xv.z, w2v.y, acc[i].y);
            acc[i].y = fmaf(xv.w, w3.y, acc[i].y);
            acc[i].z = fmaf(xv.x, w0.z, acc[i].z);
            acc[i].z = fmaf(xv.y, w1v.z, acc[i].z);
            acc[i].z = fmaf(xv.z, w2v.z, acc[i].z);
            acc[i].z = fmaf(xv.w, w3.z, acc[i].z);
            acc[i].w = fmaf(xv.x, w0.w, acc[i].w);
            acc[i].w = fmaf(xv.y, w1v.w, acc[i].w);
            acc[i].w = fmaf(xv.z, w2v.w, acc[i].w);
            acc[i].w = fmaf(xv.w, w3.w, acc[i].w);
        }
    }
    float4 w2v = ((const float4*)w2)[cg];
    float b2v = b2[0];
#pragma unroll
    for (int i = 0; i < 4; ++i) {
        float v = tanhf(acc[i].x) * w2v.x + tanhf(acc[i].y) * w2v.y
                + tanhf(acc[i].z) * w2v.z + tanhf(acc[i].w) * w2v.w;
        v += __shfl_xor(v, 1);
        v += __shfl_xor(v, 2);
        v += __shfl_xor(v, 4);
        v += __shfl_xor(v, 8);
        if (cg == 0) scores[rowbase + r0 + i] = v + b2v;
    }
}

// ---------------- softmax over genes within cell + weighted pool ----------------
__global__ void k_pool(const float* __restrict__ emb, const float* __restrict__ scores,
                       float* __restrict__ pooled) {
    __shared__ float sl[SUBG];
    __shared__ float red[512];
    int c = blockIdx.x;
    int t = threadIdx.x;   // 512 threads
    int base = c * SUBG;
    float lmax = -1e30f;
    for (int i = t; i < SUBG; i += 512) {
        float v = scores[base + i];
        sl[i] = v;
        lmax = fmaxf(lmax, v);
    }
    red[t] = lmax; __syncthreads();
    for (int off = 256; off > 0; off >>= 1) {
        if (t < off) red[t] = fmaxf(red[t], red[t + off]);
        __syncthreads();
    }
    float mx = red[0]; __syncthreads();
    float lsum = 0.f;
    for (int i = t; i < SUBG; i += 512) {
        float e = __expf(sl[i] - mx);
        sl[i] = e;
        lsum += e;
    }
    red[t] = lsum; __syncthreads();
    for (int off = 256; off > 0; off >>= 1) {
        if (t < off) red[t] += red[t + off];
        __syncthreads();
    }
    float inv = 1.0f / red[0];
    __syncthreads();
    int col = t & 127, grp = t >> 7;   // 4 row-groups
    float acc = 0.f;
#pragma unroll 2
    for (int s = grp; s < SUBG; s += 4)
        acc += sl[s] * emb[(long)(base + s) * 128 + col];
    red[t] = acc; __syncthreads();
    if (grp == 0)
        pooled[c * 128 + col] = (red[col] + red[128 + col] + red[256 + col] + red[384 + col]) * inv;
}

// ---------------- dense head ----------------
__global__ void k_head1(const float* __restrict__ pooled, const float* __restrict__ W,
                        const float* __restrict__ bias, float* __restrict__ Y) {
    __shared__ float row[128];
    int c = blockIdx.x, t = threadIdx.x;
    row[t] = pooled[c * 128 + t];
    __syncthreads();
    float acc = bias[t];
#pragma unroll 4
    for (int k = 0; k < 128; ++k) acc += row[k] * W[k * 128 + t];
    Y[c * 128 + t] = acc;
}

__global__ void k_headbn(const float* __restrict__ X, const float* __restrict__ g,
                         const float* __restrict__ b, float* __restrict__ Y, int cols) {
    int t = threadIdx.x;
    if (t >= cols) return;
    float s = 0.f, s2 = 0.f;
    for (int r = 0; r < CELLS; ++r) {
        float v = X[r * cols + t];
        s += v; s2 += v * v;
    }
    float mean = s * (1.0f / CELLS);
    float var = s2 * (1.0f / CELLS) - mean * mean;
    float scale = g[t] * rsqrtf(var + BNEPS);
    float shift = b[t] - mean * scale;
    for (int r = 0; r < CELLS; ++r)
        Y[r * cols + t] = fmaxf(X[r * cols + t] * scale + shift, 0.f);
}

__global__ void k_head2(const float* __restrict__ Y1, const float* __restrict__ W,
                        const float* __restrict__ bias, float* __restrict__ Y2) {
    __shared__ float row[128];
    int c = blockIdx.x, t = threadIdx.x;   // 128 threads
    row[t] = Y1[c * 128 + t];
    __syncthreads();
    if (t < 32) {
        float acc = bias[t];
#pragma unroll 4
        for (int k = 0; k < 128; ++k) acc += row[k] * W[k * 32 + t];
        Y2[c * 32 + t] = acc;
    }
}

// ---------------- launcher ----------------
extern "C" void kernel_launch(void* const* d_in, const int* in_sizes, int n_in,
                              void* d_out, int out_size, void* d_ws, size_t ws_size,
                              hipStream_t stream) {
    const float* x        = (const float*)d_in[0];
    const int*   ei       = (const int*)d_in[1];
    const float* conv1_w  = (const float*)d_in[2];
    const float* conv1_b  = (const float*)d_in[3];
    const float* bn1_g    = (const float*)d_in[4];
    const float* bn1_b    = (const float*)d_in[5];
    const float* conv2_w  = (const float*)d_in[6];
    const float* conv2_b  = (const float*)d_in[7];
    const float* bn2_g    = (const float*)d_in[8];
    const float* bn2_b    = (const float*)d_in[9];
    const float* att_w1   = (const float*)d_in[10];
    const float* att_b1   = (const float*)d_in[11];
    const float* att_w2   = (const float*)d_in[12];
    const float* att_b2   = (const float*)d_in[13];
    const float* fc_w     = (const float*)d_in[14];
    const float* fc_b     = (const float*)d_in[15];
    const float* bne_g    = (const float*)d_in[16];
    const float* bne_b    = (const float*)d_in[17];
    const float* bot_w    = (const float*)d_in[18];
    const float* bot_b    = (const float*)d_in[19];
    const float* bnb_g    = (const float*)d_in[20];
    const float* bnb_b    = (const float*)d_in[21];

    const int* src = ei;
    const int* dst = ei + EE;

    float* y_out   = (float*)d_out;            // [100,32]
    float* emb_out = y_out + CELLS * 32;       // [40000,128]

    float* ws = (float*)d_ws;
    float* F1     = ws;                              // N*H f32 (20.5 MB)
    u32*   Hb     = (u32*)(ws + (long)NN * HD);      // N*64 u32 (bf16 H, 10.25 MB)
    float* fbase  = ws + (long)NN * HD + (long)NN * 64;
    float* dis    = fbase;                     // N
    float* scores = dis + NN;                  // N
    float* part   = scores + NN;               // STATB*256
    float* sstats = part + STATB * 256;        // 256
    float* pooled = sstats + 256;              // C*H
    float* y1pre  = pooled + CELLS * HD;       // C*H
    float* y1     = y1pre + CELLS * HD;        // C*H
    float* y2pre  = y1 + CELLS * HD;           // C*32
    int* ibase    = (int*)(y2pre + CELLS * 32);
    int* deg      = ibase;                     // N
    int* cursor   = deg + NN;                  // N
    int* excl     = cursor + NN;               // N
    int* rowstart = excl + NN;                 // N+1
    int* partsc   = rowstart + NN + 1;         // NPB
    int* partx    = partsc + NPB;              // NPB
    int* csr_src  = partx + NPB;               // E

    // ---- CSR build (shared by both convs) ----
    k_zeroi<<<(2 * NN + 255) / 256, 256, 0, stream>>>(deg, 2 * NN);
    k_degcount<<<1024, 256, 0, stream>>>(dst, deg);
    k_scan1<<<NPB, 256, 0, stream>>>(deg, excl, partsc);
    k_scan2<<<1, 256, 0, stream>>>(partsc, partx);
    k_scan3<<<NPB, 256, 0, stream>>>(excl, partx, deg, rowstart, dis);
    k_fill<<<2048, 256, 0, stream>>>(src, dst, rowstart, cursor, csr_src);

    // ---- conv1 ----
    k_gemm128<<<625, 256, 0, stream>>>(x, conv1_w, Hb, nullptr);
    k_gather<<<10000, 256, 0, stream>>>(Hb, rowstart, csr_src, dis, conv1_b, F1);
    k_bnstats<<<STATB, 256, 0, stream>>>(F1, part, 250);
    k_bnfinal<<<1, 256, 0, stream>>>(part, bn1_g, bn1_b, sstats);

    // ---- conv2 (BN1+ReLU fused into GEMM staging) ----
    k_gemm128<<<625, 256, 0, stream>>>(F1, conv2_w, Hb, sstats);
    k_gather<<<10000, 256, 0, stream>>>(Hb, rowstart, csr_src, dis, conv2_b, F1);
    k_bnstats<<<STATB, 256, 0, stream>>>(F1, part, 250);
    k_bnfinal<<<1, 256, 0, stream>>>(part, bn2_g, bn2_b, sstats);

    // ---- BN2+ReLU + emb write + attention scores (fused) ----
    k_scores<<<625, 256, 0, stream>>>(F1, sstats, emb_out, att_w1, att_b1, att_w2, att_b2, scores);
    k_pool<<<CELLS, 512, 0, stream>>>(emb_out, scores, pooled);

    // ---- head ----
    k_head1<<<CELLS, 128, 0, stream>>>(pooled, fc_w, fc_b, y1pre);
    k_headbn<<<1, 128, 0, stream>>>(y1pre, bne_g, bne_b, y1, 128);
    k_head2<<<CELLS, 128, 0, stream>>>(y1, bot_w, bot_b, y2pre);
    k_headbn<<<1, 64, 0, stream>>>(y2pre, bnb_g, bnb_b, y_out, 32);
}